// Round 9
// baseline (214.460 us; speedup 1.0000x reference)
//
#include <hip/hip_runtime.h>

#define DD 64
#define FIN 128
#define BK 256        // nodes per bucket
#define MAXBUK 512    // supports n <= 131072
#define CAP 8192      // records per bucket region (mean ~4092 at E=1.6M)
#define EPB 4096      // edges per k_bucket block (16 per thread)
#define SBLK 4        // src locality blocks (src>>15, n <= 131072)
#define SSH 15

#define XS1 132       // padded x-tile stride (floats) for gemm1
#define XS2 68        // padded x-tile stride (floats) for gemm2

static __device__ __forceinline__ float4 f4fma(float a, float4 b, float4 c) {
    c.x = fmaf(a, b.x, c.x);
    c.y = fmaf(a, b.y, c.y);
    c.z = fmaf(a, b.z, c.z);
    c.w = fmaf(a, b.w, c.w);
    return c;
}

// round-to-nearest-even pack of two f32 into 2x bf16 (lo|hi)
static __device__ __forceinline__ unsigned bfpack(float lo, float hi) {
    unsigned ul = __float_as_uint(lo);
    unsigned uh = __float_as_uint(hi);
    ul += 0x7fffu + ((ul >> 16) & 1u);
    uh += 0x7fffu + ((uh >> 16) & 1u);
    return (ul >> 16) | (uh & 0xffff0000u);
}

// accumulate 8 bf16 (uint4) into 8 f32
static __device__ __forceinline__ void bfacc(uint4 v, float* a) {
    a[0] += __uint_as_float(v.x << 16);
    a[1] += __uint_as_float(v.x & 0xffff0000u);
    a[2] += __uint_as_float(v.y << 16);
    a[3] += __uint_as_float(v.y & 0xffff0000u);
    a[4] += __uint_as_float(v.z << 16);
    a[5] += __uint_as_float(v.z & 0xffff0000u);
    a[6] += __uint_as_float(v.w << 16);
    a[7] += __uint_as_float(v.w & 0xffff0000u);
}

// pass 1: bucket edges by dst>>8. dst values cached in regs across both passes.
__global__ __launch_bounds__(256) void k_bucket(const int* __restrict__ src,
                                                const int* __restrict__ dst,
                                                unsigned* __restrict__ buf,
                                                int* __restrict__ gcur,
                                                int E, int nbuk) {
    __shared__ int hist[MAXBUK];
    __shared__ int base[MAXBUK];
    int e0 = blockIdx.x * EPB;
    int e1 = min(e0 + EPB, E);
    int dreg[16];
#pragma unroll
    for (int i = 0; i < 16; ++i) {
        int e = e0 + threadIdx.x + i * 256;
        dreg[i] = (e < e1) ? dst[e] : -1;
    }
    for (int i = threadIdx.x; i < nbuk; i += 256) hist[i] = 0;
    __syncthreads();
#pragma unroll
    for (int i = 0; i < 16; ++i)
        if (dreg[i] >= 0) atomicAdd(&hist[dreg[i] >> 8], 1);
    __syncthreads();
    for (int i = threadIdx.x; i < nbuk; i += 256) {
        int c = hist[i];
        base[i] = c ? atomicAdd(&gcur[i], c) : 0;
        hist[i] = 0;  // reuse as local cursor
    }
    __syncthreads();
#pragma unroll
    for (int i = 0; i < 16; ++i) {
        int d = dreg[i];
        if (d >= 0) {
            int e = e0 + threadIdx.x + i * 256;
            int b = d >> 8;
            int off = base[b] + atomicAdd(&hist[b], 1);
            if (off < CAP)
                buf[(size_t)b * CAP + off] = ((unsigned)src[e] << 8) | ((unsigned)d & 255u);
        }
    }
}

// pass 2: one workgroup per bucket. Per-(node, src-block) histogram so each
// node's edge list is emitted grouped by src block (L2 phase locality).
__global__ __launch_bounds__(256) void k_csr(const unsigned* __restrict__ buf,
                                             const int* __restrict__ gcur,
                                             int* __restrict__ rowptr,
                                             float* __restrict__ rs,
                                             int* __restrict__ es, int n, int nbuk) {
    __shared__ int cnt[BK * SBLK];
    __shared__ int cur[BK * SBLK];
    __shared__ int excl[BK];
    __shared__ int wsum[4];
    __shared__ int pw[4];
    __shared__ int sbase;
    int b = blockIdx.x;
    int tid = threadIdx.x;
    int lane = tid & 63, wid = tid >> 6;
    // inline exclusive prefix: base = sum gcur[0..b)
    int partial = 0;
    for (int i = tid; i < b; i += 256) partial += gcur[i];
    for (int o = 32; o; o >>= 1) partial += __shfl_down(partial, o, 64);
    if (lane == 0) pw[wid] = partial;
    for (int i = tid; i < BK * SBLK; i += 256) { cnt[i] = 0; cur[i] = 0; }
    __syncthreads();
    if (tid == 0) sbase = pw[0] + pw[1] + pw[2] + pw[3];
    __syncthreads();
    int base = sbase;
    int count = gcur[b];
    const unsigned* rec = buf + (size_t)b * CAP;
    for (int i = tid; i < count; i += 256) {
        unsigned r = rec[i];
        atomicAdd(&cnt[(r & (BK - 1)) * SBLK + (r >> (8 + SSH))], 1);
    }
    __syncthreads();
    int c0 = cnt[tid * SBLK], c1 = cnt[tid * SBLK + 1];
    int c2 = cnt[tid * SBLK + 2], c3 = cnt[tid * SBLK + 3];
    int v = c0 + c1 + c2 + c3;
    int s = v;
    for (int off = 1; off < 64; off <<= 1) {
        int t = __shfl_up(s, off, 64);
        if (lane >= off) s += t;
    }
    if (lane == 63) wsum[wid] = s;
    // rewrite own cnt slots as within-node exclusive offsets
    cnt[tid * SBLK] = 0;
    cnt[tid * SBLK + 1] = c0;
    cnt[tid * SBLK + 2] = c0 + c1;
    cnt[tid * SBLK + 3] = c0 + c1 + c2;
    __syncthreads();
    int wo = 0;
    for (int w = 0; w < wid; ++w) wo += wsum[w];
    excl[tid] = s - v + wo;
    __syncthreads();
    int node = b * BK + tid;
    if (node < n) {
        rowptr[node] = base + excl[tid];
        rs[node] = rsqrtf((float)(v + 1));  // +1 self-loop
    }
    if (tid == 0 && b == nbuk - 1) rowptr[n] = base + count;
    for (int i = tid; i < count; i += 256) {
        unsigned r = rec[i];
        int local = r & (BK - 1);
        int sb = r >> (8 + SSH);
        int pos = base + excl[local] + cnt[local * SBLK + sb] +
                  atomicAdd(&cur[local * SBLK + sb], 1);
        es[pos] = (int)(r >> 8);
    }
}

// LDS-tiled GEMM: out[64rows x 64cols] per block, thread = 4x4 tile.
// hpb[row][col] = bf16((x[row,:] @ W[:,col]) * rs[row])
__global__ __launch_bounds__(256) void k_gemm1(const float* __restrict__ x,
                                               const float* __restrict__ W,
                                               const float* __restrict__ rs,
                                               unsigned* __restrict__ hpb, int n) {
    __shared__ float sx[64 * XS1];
    __shared__ float sW[FIN * DD];
    int row0 = blockIdx.x * 64;
    for (int i = threadIdx.x; i < FIN * DD / 4; i += 256)
        ((float4*)sW)[i] = ((const float4*)W)[i];
    for (int i = threadIdx.x; i < 64 * FIN / 4; i += 256) {
        int r = i >> 5;           // 32 float4 per row
        int c = i & 31;
        int row = row0 + r;
        float4 v = make_float4(0.f, 0.f, 0.f, 0.f);
        if (row < n) v = *(const float4*)(x + (size_t)row * FIN + c * 4);
        *(float4*)(sx + r * XS1 + c * 4) = v;
    }
    __syncthreads();
    int col4 = (threadIdx.x & 15) * 4;
    int rowg = threadIdx.x >> 4;  // 0..15
    float4 acc[4] = {make_float4(0,0,0,0), make_float4(0,0,0,0),
                     make_float4(0,0,0,0), make_float4(0,0,0,0)};
#pragma unroll 8
    for (int k = 0; k < FIN; k += 4) {
        float4 w0 = *(const float4*)(sW + k * DD + col4);
        float4 w1 = *(const float4*)(sW + (k + 1) * DD + col4);
        float4 w2 = *(const float4*)(sW + (k + 2) * DD + col4);
        float4 w3 = *(const float4*)(sW + (k + 3) * DD + col4);
#pragma unroll
        for (int r = 0; r < 4; ++r) {
            float4 xv = *(const float4*)(sx + (rowg * 4 + r) * XS1 + k);
            acc[r] = f4fma(xv.x, w0, acc[r]);
            acc[r] = f4fma(xv.y, w1, acc[r]);
            acc[r] = f4fma(xv.z, w2, acc[r]);
            acc[r] = f4fma(xv.w, w3, acc[r]);
        }
    }
#pragma unroll
    for (int r = 0; r < 4; ++r) {
        int row = row0 + rowg * 4 + r;
        if (row < n) {
            float sc = rs[row];
            uint2 pk;
            pk.x = bfpack(acc[r].x * sc, acc[r].y * sc);
            pk.y = bfpack(acc[r].z * sc, acc[r].w * sc);
            *(uint2*)(hpb + (size_t)row * 32 + (col4 >> 1)) = pk;
        }
    }
}

// hpb[row][col] = bf16((relu(a[row,:]) @ W[:,col]) * rs[row])
__global__ __launch_bounds__(256) void k_gemm2(const float* __restrict__ a,
                                               const float* __restrict__ W,
                                               const float* __restrict__ rs,
                                               unsigned* __restrict__ hpb, int n) {
    __shared__ float sx[64 * XS2];
    __shared__ float sW[DD * DD];
    int row0 = blockIdx.x * 64;
    for (int i = threadIdx.x; i < DD * DD / 4; i += 256)
        ((float4*)sW)[i] = ((const float4*)W)[i];
    for (int i = threadIdx.x; i < 64 * DD / 4; i += 256) {
        int r = i >> 4;           // 16 float4 per row
        int c = i & 15;
        int row = row0 + r;
        float4 v = make_float4(0.f, 0.f, 0.f, 0.f);
        if (row < n) {
            v = *(const float4*)(a + (size_t)row * DD + c * 4);
            v.x = fmaxf(v.x, 0.f); v.y = fmaxf(v.y, 0.f);
            v.z = fmaxf(v.z, 0.f); v.w = fmaxf(v.w, 0.f);
        }
        *(float4*)(sx + r * XS2 + c * 4) = v;
    }
    __syncthreads();
    int col4 = (threadIdx.x & 15) * 4;
    int rowg = threadIdx.x >> 4;
    float4 acc[4] = {make_float4(0,0,0,0), make_float4(0,0,0,0),
                     make_float4(0,0,0,0), make_float4(0,0,0,0)};
#pragma unroll 8
    for (int k = 0; k < DD; k += 4) {
        float4 w0 = *(const float4*)(sW + k * DD + col4);
        float4 w1 = *(const float4*)(sW + (k + 1) * DD + col4);
        float4 w2 = *(const float4*)(sW + (k + 2) * DD + col4);
        float4 w3 = *(const float4*)(sW + (k + 3) * DD + col4);
#pragma unroll
        for (int r = 0; r < 4; ++r) {
            float4 xv = *(const float4*)(sx + (rowg * 4 + r) * XS2 + k);
            acc[r] = f4fma(xv.x, w0, acc[r]);
            acc[r] = f4fma(xv.y, w1, acc[r]);
            acc[r] = f4fma(xv.z, w2, acc[r]);
            acc[r] = f4fma(xv.w, w3, acc[r]);
        }
    }
#pragma unroll
    for (int r = 0; r < 4; ++r) {
        int row = row0 + rowg * 4 + r;
        if (row < n) {
            float sc = rs[row];
            uint2 pk;
            pk.x = bfpack(acc[r].x * sc, acc[r].y * sc);
            pk.y = bfpack(acc[r].z * sc, acc[r].w * sc);
            *(uint2*)(hpb + (size_t)row * 32 + (col4 >> 1)) = pk;
        }
    }
}

// gather aggregation: 4 nodes per wave; per node 2 edge-slots x 8 lanes (uint4).
// Each slot walks a consecutive half of the src-block-sorted edge list, 4-deep.
// out[d] = b + pert[d] + rs[d]*(hp[d] + sum hp[src])
__global__ __launch_bounds__(256) void k_agg(const uint4* __restrict__ hp4,
                                             const int* __restrict__ es,
                                             const int* __restrict__ rowptr,
                                             const float* __restrict__ rs,
                                             const float* __restrict__ b,
                                             const float* __restrict__ pert,
                                             float* __restrict__ outp, int n) {
    int lane = threadIdx.x & 63;
    int wv = threadIdx.x >> 6;
    int g = lane >> 4;            // node sub-group 0..3
    int sub = lane & 15;
    int eslot = sub >> 3;         // 0..1
    int q = sub & 7;              // uint4 index within 128B row
    int node = (blockIdx.x * 4 + wv) * 4 + g;
    bool alive = node < n;
    int nc = alive ? node : 0;
    int e0 = rowptr[nc];
    int e1 = alive ? rowptr[nc + 1] : e0;
    int half = (e1 - e0 + 1) >> 1;
    int e    = eslot ? (e0 + half) : e0;
    int send = eslot ? e1 : (e0 + half);
    float A[8] = {0,0,0,0,0,0,0,0};
    float B[8] = {0,0,0,0,0,0,0,0};
    float C[8] = {0,0,0,0,0,0,0,0};
    float D[8] = {0,0,0,0,0,0,0,0};
    if (alive && eslot == 0) bfacc(hp4[(size_t)nc * 8 + q], A);  // self-loop
    for (; e + 3 < send; e += 4) {
        int i0 = es[e], i1 = es[e + 1], i2 = es[e + 2], i3 = es[e + 3];
        uint4 va = hp4[(size_t)i0 * 8 + q];
        uint4 vb = hp4[(size_t)i1 * 8 + q];
        uint4 vc = hp4[(size_t)i2 * 8 + q];
        uint4 vd = hp4[(size_t)i3 * 8 + q];
        bfacc(va, A); bfacc(vb, B); bfacc(vc, C); bfacc(vd, D);
    }
    for (; e < send; ++e) bfacc(hp4[(size_t)es[e] * 8 + q], A);
#pragma unroll
    for (int j = 0; j < 8; ++j) {
        float v = (A[j] + B[j]) + (C[j] + D[j]);
        v += __shfl_xor(v, 8, 64);  // combine the 2 edge slots
        A[j] = v;
    }
    if (alive && eslot == 0) {
        float r = rs[nc];
        size_t o = (size_t)nc * DD + q * 8;
        float4 p0 = *(const float4*)(pert + o);
        float4 p1 = *(const float4*)(pert + o + 4);
        float4 b0 = *(const float4*)(b + q * 8);
        float4 b1 = *(const float4*)(b + q * 8 + 4);
        float4 r0, r1;
        r0.x = fmaf(r, A[0], b0.x + p0.x);
        r0.y = fmaf(r, A[1], b0.y + p0.y);
        r0.z = fmaf(r, A[2], b0.z + p0.z);
        r0.w = fmaf(r, A[3], b0.w + p0.w);
        r1.x = fmaf(r, A[4], b1.x + p1.x);
        r1.y = fmaf(r, A[5], b1.y + p1.y);
        r1.z = fmaf(r, A[6], b1.z + p1.z);
        r1.w = fmaf(r, A[7], b1.w + p1.w);
        *(float4*)(outp + o) = r0;
        *(float4*)(outp + o + 4) = r1;
    }
}

extern "C" void kernel_launch(void* const* d_in, const int* in_sizes, int n_in,
                              void* d_out, int out_size, void* d_ws, size_t ws_size,
                              hipStream_t stream) {
    const float* x  = (const float*)d_in[0];
    const int*   ei = (const int*)d_in[1];
    const float* W1 = (const float*)d_in[2];
    const float* b1 = (const float*)d_in[3];
    const float* W2 = (const float*)d_in[4];
    const float* b2 = (const float*)d_in[5];
    const float* p1 = (const float*)d_in[6];
    const float* p2 = (const float*)d_in[7];
    float* out = (float*)d_out;

    int n = in_sizes[0] / FIN;
    int E = in_sizes[1] / 2;
    const int* src = ei;
    const int* dst = ei + E;
    int nbuk = (n + BK - 1) / BK;  // 391 for n=100k

    char* ws = (char*)d_ws;
    size_t off = 0;
    int* gcur   = (int*)(ws + off); off += sizeof(int) * MAXBUK;
    int* rowptr = (int*)(ws + off); off += sizeof(int) * (size_t)(n + 1);
    float* rs   = (float*)(ws + off); off += sizeof(float) * (size_t)n;
    int* es     = (int*)(ws + off); off += sizeof(int) * (size_t)E;
    off = (off + 15) & ~(size_t)15;
    unsigned* buf = (unsigned*)(ws + off);
    off += sizeof(unsigned) * (size_t)nbuk * CAP;
    off = (off + 15) & ~(size_t)15;
    unsigned* hpb = (unsigned*)(ws + off);      // bf16 [n][64] = n*128 bytes
    off += (size_t)n * 128;
    float* agg1 = (float*)(ws + off); off += sizeof(float) * (size_t)n * DD;

    int ab = (n + 15) / 16;        // 4 nodes per wave, 4 waves per block
    int gb = (n + 63) / 64;
    int bb = (E + EPB - 1) / EPB;

    hipMemsetAsync(gcur, 0, sizeof(int) * MAXBUK, stream);
    k_bucket<<<bb, 256, 0, stream>>>(src, dst, buf, gcur, E, nbuk);
    k_csr<<<nbuk, 256, 0, stream>>>(buf, gcur, rowptr, rs, es, n, nbuk);

    k_gemm1<<<gb, 256, 0, stream>>>(x, W1, rs, hpb, n);
    k_agg<<<ab, 256, 0, stream>>>((const uint4*)hpb, es, rowptr, rs, b1, p1, agg1, n);

    k_gemm2<<<gb, 256, 0, stream>>>(agg1, W2, rs, hpb, n);
    k_agg<<<ab, 256, 0, stream>>>((const uint4*)hpb, es, rowptr, rs, b2, p2, out, n);
}

// Round 10
// 180.253 us; speedup vs baseline: 1.1898x; 1.1898x over previous
//
#include <hip/hip_runtime.h>

#define DD 64
#define FIN 128
#define BK 256        // nodes per bucket
#define MAXBUK 512    // supports n <= 131072
#define CAP 8192      // records per bucket region (mean ~4092 at E=1.6M)
#define ESCAP 12288   // padded es slots per bucket (>= CAP + 15*BK/... safe bound)
#define EPB 4096      // edges per k_bucket block (16 per thread)

#define XS1 132       // padded x-tile stride (floats) for gemm1
#define XS2 68        // padded x-tile stride (floats) for gemm2

static __device__ __forceinline__ float4 f4fma(float a, float4 b, float4 c) {
    c.x = fmaf(a, b.x, c.x);
    c.y = fmaf(a, b.y, c.y);
    c.z = fmaf(a, b.z, c.z);
    c.w = fmaf(a, b.w, c.w);
    return c;
}

// round-to-nearest-even pack of two f32 into 2x bf16 (lo|hi)
static __device__ __forceinline__ unsigned bfpack(float lo, float hi) {
    unsigned ul = __float_as_uint(lo);
    unsigned uh = __float_as_uint(hi);
    ul += 0x7fffu + ((ul >> 16) & 1u);
    uh += 0x7fffu + ((uh >> 16) & 1u);
    return (ul >> 16) | (uh & 0xffff0000u);
}

// accumulate 8 bf16 (uint4) into 8 f32
static __device__ __forceinline__ void bfacc(uint4 v, float* a) {
    a[0] += __uint_as_float(v.x << 16);
    a[1] += __uint_as_float(v.x & 0xffff0000u);
    a[2] += __uint_as_float(v.y << 16);
    a[3] += __uint_as_float(v.y & 0xffff0000u);
    a[4] += __uint_as_float(v.z << 16);
    a[5] += __uint_as_float(v.z & 0xffff0000u);
    a[6] += __uint_as_float(v.w << 16);
    a[7] += __uint_as_float(v.w & 0xffff0000u);
}

// pass 1: bucket edges by dst>>8. dst values cached in regs across both passes.
__global__ __launch_bounds__(256) void k_bucket(const int* __restrict__ src,
                                                const int* __restrict__ dst,
                                                unsigned* __restrict__ buf,
                                                int* __restrict__ gcur,
                                                int E, int nbuk) {
    __shared__ int hist[MAXBUK];
    __shared__ int base[MAXBUK];
    int e0 = blockIdx.x * EPB;
    int e1 = min(e0 + EPB, E);
    int dreg[16];
#pragma unroll
    for (int i = 0; i < 16; ++i) {
        int e = e0 + threadIdx.x + i * 256;
        dreg[i] = (e < e1) ? dst[e] : -1;
    }
    for (int i = threadIdx.x; i < nbuk; i += 256) hist[i] = 0;
    __syncthreads();
#pragma unroll
    for (int i = 0; i < 16; ++i)
        if (dreg[i] >= 0) atomicAdd(&hist[dreg[i] >> 8], 1);
    __syncthreads();
    for (int i = threadIdx.x; i < nbuk; i += 256) {
        int c = hist[i];
        base[i] = c ? atomicAdd(&gcur[i], c) : 0;
        hist[i] = 0;  // reuse as local cursor
    }
    __syncthreads();
#pragma unroll
    for (int i = 0; i < 16; ++i) {
        int d = dreg[i];
        if (d >= 0) {
            int e = e0 + threadIdx.x + i * 256;
            int b = d >> 8;
            int off = base[b] + atomicAdd(&hist[b], 1);
            if (off < CAP)
                buf[(size_t)b * CAP + off] = ((unsigned)src[e] << 8) | ((unsigned)d & 255u);
        }
    }
}

// pass 2: one workgroup per bucket. Per-node histogram -> padded (x16) scan ->
// es region at fixed b*ESCAP. Pads point at dummy row (index n, zeroed in gemm).
__global__ __launch_bounds__(256) void k_csr(const unsigned* __restrict__ buf,
                                             const int* __restrict__ gcur,
                                             int* __restrict__ rowptr,
                                             int* __restrict__ lenp,
                                             float* __restrict__ rs,
                                             int* __restrict__ es, int n, int dummy) {
    __shared__ int cnt[BK];
    __shared__ int excl[BK];
    __shared__ int cur[BK];
    __shared__ int wsum[4];
    int b = blockIdx.x;
    int tid = threadIdx.x;
    int lane = tid & 63, wid = tid >> 6;
    cnt[tid] = 0;
    cur[tid] = 0;
    __syncthreads();
    int count = gcur[b];
    const unsigned* rec = buf + (size_t)b * CAP;
    for (int i = tid; i < count; i += 256)
        atomicAdd(&cnt[rec[i] & (BK - 1)], 1);
    __syncthreads();
    int v = cnt[tid];
    int pv = (v + 15) & ~15;  // padded to multiple of 16
    int s = pv;
    for (int off = 1; off < 64; off <<= 1) {
        int t = __shfl_up(s, off, 64);
        if (lane >= off) s += t;
    }
    if (lane == 63) wsum[wid] = s;
    __syncthreads();
    int wo = 0;
    for (int w = 0; w < wid; ++w) wo += wsum[w];
    excl[tid] = s - pv + wo;
    __syncthreads();
    int node = b * BK + tid;
    int base = b * ESCAP;
    if (node < n) {
        rowptr[node] = base + excl[tid];
        lenp[node] = pv;
        rs[node] = rsqrtf((float)(v + 1));  // +1 self-loop
    }
    // place real records
    for (int i = tid; i < count; i += 256) {
        unsigned r = rec[i];
        int local = r & (BK - 1);
        int pos = base + excl[local] + atomicAdd(&cur[local], 1);
        es[pos] = (int)(r >> 8);
    }
    // pad own node's tail with dummy index (disjoint range, no sync needed)
    int st = base + excl[tid];
    for (int i = v; i < pv; ++i) es[st + i] = dummy;
}

// LDS-tiled GEMM: out[64rows x 64cols] per block, thread = 4x4 tile.
// hpb[row][col] = bf16((x[row,:] @ W[:,col]) * rs[row]); rows >= n zeroed.
__global__ __launch_bounds__(256) void k_gemm1(const float* __restrict__ x,
                                               const float* __restrict__ W,
                                               const float* __restrict__ rs,
                                               unsigned* __restrict__ hpb, int n) {
    __shared__ float sx[64 * XS1];
    __shared__ float sW[FIN * DD];
    int row0 = blockIdx.x * 64;
    for (int i = threadIdx.x; i < FIN * DD / 4; i += 256)
        ((float4*)sW)[i] = ((const float4*)W)[i];
    for (int i = threadIdx.x; i < 64 * FIN / 4; i += 256) {
        int r = i >> 5;           // 32 float4 per row
        int c = i & 31;
        int row = row0 + r;
        float4 v = make_float4(0.f, 0.f, 0.f, 0.f);
        if (row < n) v = *(const float4*)(x + (size_t)row * FIN + c * 4);
        *(float4*)(sx + r * XS1 + c * 4) = v;
    }
    __syncthreads();
    int col4 = (threadIdx.x & 15) * 4;
    int rowg = threadIdx.x >> 4;  // 0..15
    float4 acc[4] = {make_float4(0,0,0,0), make_float4(0,0,0,0),
                     make_float4(0,0,0,0), make_float4(0,0,0,0)};
#pragma unroll 8
    for (int k = 0; k < FIN; k += 4) {
        float4 w0 = *(const float4*)(sW + k * DD + col4);
        float4 w1 = *(const float4*)(sW + (k + 1) * DD + col4);
        float4 w2 = *(const float4*)(sW + (k + 2) * DD + col4);
        float4 w3 = *(const float4*)(sW + (k + 3) * DD + col4);
#pragma unroll
        for (int r = 0; r < 4; ++r) {
            float4 xv = *(const float4*)(sx + (rowg * 4 + r) * XS1 + k);
            acc[r] = f4fma(xv.x, w0, acc[r]);
            acc[r] = f4fma(xv.y, w1, acc[r]);
            acc[r] = f4fma(xv.z, w2, acc[r]);
            acc[r] = f4fma(xv.w, w3, acc[r]);
        }
    }
#pragma unroll
    for (int r = 0; r < 4; ++r) {
        int row = row0 + rowg * 4 + r;
        uint2 pk = make_uint2(0u, 0u);
        if (row < n) {
            float sc = rs[row];
            pk.x = bfpack(acc[r].x * sc, acc[r].y * sc);
            pk.y = bfpack(acc[r].z * sc, acc[r].w * sc);
        }
        *(uint2*)(hpb + (size_t)row * 32 + (col4 >> 1)) = pk;
    }
}

// hpb[row][col] = bf16((relu(a[row,:]) @ W[:,col]) * rs[row]); rows >= n zeroed.
__global__ __launch_bounds__(256) void k_gemm2(const float* __restrict__ a,
                                               const float* __restrict__ W,
                                               const float* __restrict__ rs,
                                               unsigned* __restrict__ hpb, int n) {
    __shared__ float sx[64 * XS2];
    __shared__ float sW[DD * DD];
    int row0 = blockIdx.x * 64;
    for (int i = threadIdx.x; i < DD * DD / 4; i += 256)
        ((float4*)sW)[i] = ((const float4*)W)[i];
    for (int i = threadIdx.x; i < 64 * DD / 4; i += 256) {
        int r = i >> 4;           // 16 float4 per row
        int c = i & 15;
        int row = row0 + r;
        float4 v = make_float4(0.f, 0.f, 0.f, 0.f);
        if (row < n) {
            v = *(const float4*)(a + (size_t)row * DD + c * 4);
            v.x = fmaxf(v.x, 0.f); v.y = fmaxf(v.y, 0.f);
            v.z = fmaxf(v.z, 0.f); v.w = fmaxf(v.w, 0.f);
        }
        *(float4*)(sx + r * XS2 + c * 4) = v;
    }
    __syncthreads();
    int col4 = (threadIdx.x & 15) * 4;
    int rowg = threadIdx.x >> 4;
    float4 acc[4] = {make_float4(0,0,0,0), make_float4(0,0,0,0),
                     make_float4(0,0,0,0), make_float4(0,0,0,0)};
#pragma unroll 8
    for (int k = 0; k < DD; k += 4) {
        float4 w0 = *(const float4*)(sW + k * DD + col4);
        float4 w1 = *(const float4*)(sW + (k + 1) * DD + col4);
        float4 w2 = *(const float4*)(sW + (k + 2) * DD + col4);
        float4 w3 = *(const float4*)(sW + (k + 3) * DD + col4);
#pragma unroll
        for (int r = 0; r < 4; ++r) {
            float4 xv = *(const float4*)(sx + (rowg * 4 + r) * XS2 + k);
            acc[r] = f4fma(xv.x, w0, acc[r]);
            acc[r] = f4fma(xv.y, w1, acc[r]);
            acc[r] = f4fma(xv.z, w2, acc[r]);
            acc[r] = f4fma(xv.w, w3, acc[r]);
        }
    }
#pragma unroll
    for (int r = 0; r < 4; ++r) {
        int row = row0 + rowg * 4 + r;
        uint2 pk = make_uint2(0u, 0u);
        if (row < n) {
            float sc = rs[row];
            pk.x = bfpack(acc[r].x * sc, acc[r].y * sc);
            pk.y = bfpack(acc[r].z * sc, acc[r].w * sc);
        }
        *(uint2*)(hpb + (size_t)row * 32 + (col4 >> 1)) = pk;
    }
}

// gather aggregation: 4 nodes/wave, 16 lanes/node (2 edge-slots x 8 lanes).
// Edge lists padded to x16 with dummy row n (zero, L1-hot) -> branchless inner
// loop: 1 coalesced es load + shfl broadcast + 8 gathers in flight per slot.
__global__ __launch_bounds__(256) void k_agg(const uint4* __restrict__ hp4,
                                             const int* __restrict__ es,
                                             const int* __restrict__ rowptr,
                                             const int* __restrict__ lenp,
                                             const float* __restrict__ rs,
                                             const float* __restrict__ b,
                                             const float* __restrict__ pert,
                                             float* __restrict__ outp, int n) {
    int lane = threadIdx.x & 63;
    int wv = threadIdx.x >> 6;
    int g = lane >> 4;            // node sub-group 0..3
    int sub = lane & 15;
    int eslot = sub >> 3;         // 0..1
    int q = sub & 7;              // uint4 index within 128B row
    int node = (blockIdx.x * 4 + wv) * 4 + g;
    bool alive = node < n;
    int nc = alive ? node : 0;
    int e0 = rowptr[nc];
    int len = alive ? lenp[nc] : 0;
    float A[8] = {0,0,0,0,0,0,0,0};
    float B[8] = {0,0,0,0,0,0,0,0};
    float C[8] = {0,0,0,0,0,0,0,0};
    float D[8] = {0,0,0,0,0,0,0,0};
    if (alive && eslot == 0) bfacc(hp4[(size_t)nc * 8 + q], A);  // self-loop
    for (int eb = e0; eb < e0 + len; eb += 16) {
        int idx = es[eb + sub];   // 16 coalesced indices for this node
        int i0 = __shfl(idx, 0 + eslot, 16);
        int i1 = __shfl(idx, 2 + eslot, 16);
        int i2 = __shfl(idx, 4 + eslot, 16);
        int i3 = __shfl(idx, 6 + eslot, 16);
        int i4 = __shfl(idx, 8 + eslot, 16);
        int i5 = __shfl(idx, 10 + eslot, 16);
        int i6 = __shfl(idx, 12 + eslot, 16);
        int i7 = __shfl(idx, 14 + eslot, 16);
        uint4 v0 = hp4[(size_t)i0 * 8 + q];
        uint4 v1 = hp4[(size_t)i1 * 8 + q];
        uint4 v2 = hp4[(size_t)i2 * 8 + q];
        uint4 v3 = hp4[(size_t)i3 * 8 + q];
        uint4 v4 = hp4[(size_t)i4 * 8 + q];
        uint4 v5 = hp4[(size_t)i5 * 8 + q];
        uint4 v6 = hp4[(size_t)i6 * 8 + q];
        uint4 v7 = hp4[(size_t)i7 * 8 + q];
        bfacc(v0, A); bfacc(v1, B); bfacc(v2, C); bfacc(v3, D);
        bfacc(v4, A); bfacc(v5, B); bfacc(v6, C); bfacc(v7, D);
    }
#pragma unroll
    for (int j = 0; j < 8; ++j) {
        float v = (A[j] + B[j]) + (C[j] + D[j]);
        v += __shfl_xor(v, 8, 64);  // combine the 2 edge slots
        A[j] = v;
    }
    if (alive && eslot == 0) {
        float r = rs[nc];
        size_t o = (size_t)nc * DD + q * 8;
        float4 p0 = *(const float4*)(pert + o);
        float4 p1 = *(const float4*)(pert + o + 4);
        float4 b0 = *(const float4*)(b + q * 8);
        float4 b1 = *(const float4*)(b + q * 8 + 4);
        float4 r0, r1;
        r0.x = fmaf(r, A[0], b0.x + p0.x);
        r0.y = fmaf(r, A[1], b0.y + p0.y);
        r0.z = fmaf(r, A[2], b0.z + p0.z);
        r0.w = fmaf(r, A[3], b0.w + p0.w);
        r1.x = fmaf(r, A[4], b1.x + p1.x);
        r1.y = fmaf(r, A[5], b1.y + p1.y);
        r1.z = fmaf(r, A[6], b1.z + p1.z);
        r1.w = fmaf(r, A[7], b1.w + p1.w);
        *(float4*)(outp + o) = r0;
        *(float4*)(outp + o + 4) = r1;
    }
}

extern "C" void kernel_launch(void* const* d_in, const int* in_sizes, int n_in,
                              void* d_out, int out_size, void* d_ws, size_t ws_size,
                              hipStream_t stream) {
    const float* x  = (const float*)d_in[0];
    const int*   ei = (const int*)d_in[1];
    const float* W1 = (const float*)d_in[2];
    const float* b1 = (const float*)d_in[3];
    const float* W2 = (const float*)d_in[4];
    const float* b2 = (const float*)d_in[5];
    const float* p1 = (const float*)d_in[6];
    const float* p2 = (const float*)d_in[7];
    float* out = (float*)d_out;

    int n = in_sizes[0] / FIN;
    int E = in_sizes[1] / 2;
    const int* src = ei;
    const int* dst = ei + E;
    int nbuk = (n + BK - 1) / BK;  // 391 for n=100k
    int gb = (n + 63) / 64;

    char* ws = (char*)d_ws;
    size_t off = 0;
    int* gcur   = (int*)(ws + off); off += sizeof(int) * MAXBUK;
    int* rowptr = (int*)(ws + off); off += sizeof(int) * (size_t)n;
    int* lenp   = (int*)(ws + off); off += sizeof(int) * (size_t)n;
    float* rs   = (float*)(ws + off); off += sizeof(float) * (size_t)n;
    int* es     = (int*)(ws + off); off += sizeof(int) * (size_t)nbuk * ESCAP;
    off = (off + 15) & ~(size_t)15;
    unsigned* buf = (unsigned*)(ws + off);
    off += sizeof(unsigned) * (size_t)nbuk * CAP;
    off = (off + 15) & ~(size_t)15;
    unsigned* hpb = (unsigned*)(ws + off);      // bf16 [gb*64][64], rows>=n zero
    off += (size_t)gb * 64 * 128;
    float* agg1 = (float*)(ws + off); off += sizeof(float) * (size_t)n * DD;

    int ab = (n + 15) / 16;        // 4 nodes per wave, 4 waves per block
    int bb = (E + EPB - 1) / EPB;

    hipMemsetAsync(gcur, 0, sizeof(int) * MAXBUK, stream);
    k_bucket<<<bb, 256, 0, stream>>>(src, dst, buf, gcur, E, nbuk);
    k_csr<<<nbuk, 256, 0, stream>>>(buf, gcur, rowptr, lenp, rs, es, n, n);

    k_gemm1<<<gb, 256, 0, stream>>>(x, W1, rs, hpb, n);
    k_agg<<<ab, 256, 0, stream>>>((const uint4*)hpb, es, rowptr, lenp, rs, b1, p1, agg1, n);

    k_gemm2<<<gb, 256, 0, stream>>>(agg1, W2, rs, hpb, n);
    k_agg<<<ab, 256, 0, stream>>>((const uint4*)hpb, es, rowptr, lenp, rs, b2, p2, out, n);
}

// Round 11
// 168.623 us; speedup vs baseline: 1.2718x; 1.0690x over previous
//
#include <hip/hip_runtime.h>

#define DD 64
#define FIN 128
#define BK 256        // nodes per bucket
#define MAXBUK 512    // supports n <= 131072
#define CAP 8192      // records per bucket region (mean ~4092 at E=1.6M)
#define ESCAP 12288   // padded es slots per bucket (8192 + 256*15 = 12032 max)
#define EPB 4096      // edges per k_bucket block (16 per thread)

typedef _Float16 half8 __attribute__((ext_vector_type(8)));
typedef float f32x4 __attribute__((ext_vector_type(4)));

// accumulate 8 f16 (uint4) into 8 f32
static __device__ __forceinline__ void f16acc(uint4 v, float* a) {
    union { unsigned u; _Float16 h[2]; } t0, t1, t2, t3;
    t0.u = v.x; t1.u = v.y; t2.u = v.z; t3.u = v.w;
    a[0] += (float)t0.h[0]; a[1] += (float)t0.h[1];
    a[2] += (float)t1.h[0]; a[3] += (float)t1.h[1];
    a[4] += (float)t2.h[0]; a[5] += (float)t2.h[1];
    a[6] += (float)t3.h[0]; a[7] += (float)t3.h[1];
}

// pass 1: bucket edges by dst>>8. dst values cached in regs across both passes.
__global__ __launch_bounds__(256) void k_bucket(const int* __restrict__ src,
                                                const int* __restrict__ dst,
                                                unsigned* __restrict__ buf,
                                                int* __restrict__ gcur,
                                                int E, int nbuk) {
    __shared__ int hist[MAXBUK];
    __shared__ int base[MAXBUK];
    int e0 = blockIdx.x * EPB;
    int e1 = min(e0 + EPB, E);
    int dreg[16];
#pragma unroll
    for (int i = 0; i < 16; ++i) {
        int e = e0 + threadIdx.x + i * 256;
        dreg[i] = (e < e1) ? dst[e] : -1;
    }
    for (int i = threadIdx.x; i < nbuk; i += 256) hist[i] = 0;
    __syncthreads();
#pragma unroll
    for (int i = 0; i < 16; ++i)
        if (dreg[i] >= 0) atomicAdd(&hist[dreg[i] >> 8], 1);
    __syncthreads();
    for (int i = threadIdx.x; i < nbuk; i += 256) {
        int c = hist[i];
        base[i] = c ? atomicAdd(&gcur[i], c) : 0;
        hist[i] = 0;  // reuse as local cursor
    }
    __syncthreads();
#pragma unroll
    for (int i = 0; i < 16; ++i) {
        int d = dreg[i];
        if (d >= 0) {
            int e = e0 + threadIdx.x + i * 256;
            int b = d >> 8;
            int off = base[b] + atomicAdd(&hist[b], 1);
            if (off < CAP)
                buf[(size_t)b * CAP + off] = ((unsigned)src[e] << 8) | ((unsigned)d & 255u);
        }
    }
}

// pass 2: one workgroup per bucket. Per-node histogram -> padded (x16) scan ->
// es region at fixed b*ESCAP. Pads point at dummy row (index n, zeroed in gemm).
__global__ __launch_bounds__(256) void k_csr(const unsigned* __restrict__ buf,
                                             const int* __restrict__ gcur,
                                             int* __restrict__ rowptr,
                                             int* __restrict__ lenp,
                                             float* __restrict__ rs,
                                             int* __restrict__ es, int n, int dummy) {
    __shared__ int cnt[BK];
    __shared__ int excl[BK];
    __shared__ int cur[BK];
    __shared__ int wsum[4];
    int b = blockIdx.x;
    int tid = threadIdx.x;
    int lane = tid & 63, wid = tid >> 6;
    cnt[tid] = 0;
    cur[tid] = 0;
    __syncthreads();
    int count = gcur[b];
    const unsigned* rec = buf + (size_t)b * CAP;
    for (int i = tid; i < count; i += 256)
        atomicAdd(&cnt[rec[i] & (BK - 1)], 1);
    __syncthreads();
    int v = cnt[tid];
    int pv = (v + 15) & ~15;  // padded to multiple of 16
    int s = pv;
    for (int off = 1; off < 64; off <<= 1) {
        int t = __shfl_up(s, off, 64);
        if (lane >= off) s += t;
    }
    if (lane == 63) wsum[wid] = s;
    __syncthreads();
    int wo = 0;
    for (int w = 0; w < wid; ++w) wo += wsum[w];
    excl[tid] = s - pv + wo;
    __syncthreads();
    int node = b * BK + tid;
    int base = b * ESCAP;
    if (node < n) {
        rowptr[node] = base + excl[tid];
        lenp[node] = pv;
        rs[node] = rsqrtf((float)(v + 1));  // +1 self-loop
    }
    for (int i = tid; i < count; i += 256) {
        unsigned r = rec[i];
        int local = r & (BK - 1);
        int pos = base + excl[local] + atomicAdd(&cur[local], 1);
        es[pos] = (int)(r >> 8);
    }
    int st = base + excl[tid];
    for (int i = v; i < pv; ++i) es[st + i] = dummy;
}

// transpose + f16-convert weights: Wt1[c][k] = W1[k][c], Wt2[c][k] = W2[k][c]
__global__ __launch_bounds__(256) void k_prep(const float* __restrict__ W1,
                                              const float* __restrict__ W2,
                                              _Float16* __restrict__ Wt1,
                                              _Float16* __restrict__ Wt2) {
    int tid = threadIdx.x;
    for (int i = tid; i < FIN * DD; i += 256) {
        int k = i >> 6, c = i & 63;
        Wt1[c * FIN + k] = (_Float16)W1[i];
    }
    for (int i = tid; i < DD * DD; i += 256) {
        int k = i >> 6, c = i & 63;
        Wt2[c * DD + k] = (_Float16)W2[i];
    }
}

// MFMA f16 GEMM: hpf[row][col] = f16((x[row,:] @ W[:,col]) * rs[row])
// block = 64 rows x 64 cols, 4 waves (wave = 16 rows), K=128. rows >= n zeroed.
__global__ __launch_bounds__(256) void k_gemm1(const float* __restrict__ x,
                                               const _Float16* __restrict__ Wt,
                                               const float* __restrict__ rs,
                                               _Float16* __restrict__ hpf, int n) {
    __shared__ _Float16 sx[64 * 136];
    int row0 = blockIdx.x * 64;
    int tid = threadIdx.x;
    // stage x tile as f16 (stride 136 halfs = 272B, 16B-aligned rows)
    for (int i = tid; i < 2048; i += 256) {  // 64 rows * 32 float4
        int r = i >> 5, c = i & 31;
        int row = row0 + r;
        float4 v = make_float4(0.f, 0.f, 0.f, 0.f);
        if (row < n) v = *(const float4*)(x + (size_t)row * FIN + c * 4);
        union { _Float16 h[4]; uint2 u; } t;
        t.h[0] = (_Float16)v.x; t.h[1] = (_Float16)v.y;
        t.h[2] = (_Float16)v.z; t.h[3] = (_Float16)v.w;
        *(uint2*)(sx + r * 136 + c * 4) = t.u;
    }
    __syncthreads();
    int lane = tid & 63, wave = tid >> 6;
    int r15 = lane & 15, g = lane >> 4;
    half8 a[4];
    const _Float16* ap = sx + (wave * 16 + r15) * 136 + g * 8;
#pragma unroll
    for (int kc = 0; kc < 4; ++kc) a[kc] = *(const half8*)(ap + kc * 32);
    half8 bfr[4][4];
    const _Float16* bp = Wt + (size_t)r15 * FIN + g * 8;
#pragma unroll
    for (int ct = 0; ct < 4; ++ct)
#pragma unroll
        for (int kc = 0; kc < 4; ++kc)
            bfr[ct][kc] = *(const half8*)(bp + ct * 16 * FIN + kc * 32);
    f32x4 acc[4] = {{0.f,0.f,0.f,0.f},{0.f,0.f,0.f,0.f},{0.f,0.f,0.f,0.f},{0.f,0.f,0.f,0.f}};
#pragma unroll
    for (int ct = 0; ct < 4; ++ct)
#pragma unroll
        for (int kc = 0; kc < 4; ++kc)
            acc[ct] = __builtin_amdgcn_mfma_f32_16x16x32_f16(a[kc], bfr[ct][kc], acc[ct], 0, 0, 0);
    __syncthreads();  // all LDS reads done; safe to reuse sx
    // D: row=(lane>>4)*4+reg (+wave*16), col=ct*16+(lane&15). Stage to LDS, store coalesced.
#pragma unroll
    for (int reg = 0; reg < 4; ++reg) {
        int rowl = wave * 16 + g * 4 + reg;
        int row = row0 + rowl;
        float sc = (row < n) ? rs[row] : 0.f;
#pragma unroll
        for (int ct = 0; ct < 4; ++ct)
            sx[rowl * 72 + ct * 16 + r15] = (_Float16)(acc[ct][reg] * sc);
    }
    __syncthreads();
    for (int i = tid; i < 1024; i += 256) {  // 64 rows * 16 uint2
        int r = i >> 4, q = i & 15;
        uint2 v = *(const uint2*)(sx + r * 72 + q * 4);
        *(uint2*)(hpf + (size_t)(row0 + r) * DD + q * 4) = v;
    }
}

// MFMA f16 GEMM: hpf[row][col] = f16((relu(a[row,:]) @ W[:,col]) * rs[row]), K=64
__global__ __launch_bounds__(256) void k_gemm2(const float* __restrict__ ain,
                                               const _Float16* __restrict__ Wt,
                                               const float* __restrict__ rs,
                                               _Float16* __restrict__ hpf, int n) {
    __shared__ _Float16 sx[64 * 72];
    int row0 = blockIdx.x * 64;
    int tid = threadIdx.x;
    for (int i = tid; i < 1024; i += 256) {  // 64 rows * 16 float4
        int r = i >> 4, c = i & 15;
        int row = row0 + r;
        float4 v = make_float4(0.f, 0.f, 0.f, 0.f);
        if (row < n) {
            v = *(const float4*)(ain + (size_t)row * DD + c * 4);
            v.x = fmaxf(v.x, 0.f); v.y = fmaxf(v.y, 0.f);
            v.z = fmaxf(v.z, 0.f); v.w = fmaxf(v.w, 0.f);
        }
        union { _Float16 h[4]; uint2 u; } t;
        t.h[0] = (_Float16)v.x; t.h[1] = (_Float16)v.y;
        t.h[2] = (_Float16)v.z; t.h[3] = (_Float16)v.w;
        *(uint2*)(sx + r * 72 + c * 4) = t.u;
    }
    __syncthreads();
    int lane = tid & 63, wave = tid >> 6;
    int r15 = lane & 15, g = lane >> 4;
    half8 a[2];
    const _Float16* ap = sx + (wave * 16 + r15) * 72 + g * 8;
#pragma unroll
    for (int kc = 0; kc < 2; ++kc) a[kc] = *(const half8*)(ap + kc * 32);
    half8 bfr[4][2];
    const _Float16* bp = Wt + (size_t)r15 * DD + g * 8;
#pragma unroll
    for (int ct = 0; ct < 4; ++ct)
#pragma unroll
        for (int kc = 0; kc < 2; ++kc)
            bfr[ct][kc] = *(const half8*)(bp + ct * 16 * DD + kc * 32);
    f32x4 acc[4] = {{0.f,0.f,0.f,0.f},{0.f,0.f,0.f,0.f},{0.f,0.f,0.f,0.f},{0.f,0.f,0.f,0.f}};
#pragma unroll
    for (int ct = 0; ct < 4; ++ct)
#pragma unroll
        for (int kc = 0; kc < 2; ++kc)
            acc[ct] = __builtin_amdgcn_mfma_f32_16x16x32_f16(a[kc], bfr[ct][kc], acc[ct], 0, 0, 0);
    __syncthreads();
#pragma unroll
    for (int reg = 0; reg < 4; ++reg) {
        int rowl = wave * 16 + g * 4 + reg;
        int row = row0 + rowl;
        float sc = (row < n) ? rs[row] : 0.f;
#pragma unroll
        for (int ct = 0; ct < 4; ++ct)
            sx[rowl * 72 + ct * 16 + r15] = (_Float16)(acc[ct][reg] * sc);
    }
    __syncthreads();
    for (int i = tid; i < 1024; i += 256) {
        int r = i >> 4, q = i & 15;
        uint2 v = *(const uint2*)(sx + r * 72 + q * 4);
        *(uint2*)(hpf + (size_t)(row0 + r) * DD + q * 4) = v;
    }
}

// gather aggregation: 4 nodes/wave, 16 lanes/node (2 edge-slots x 8 lanes).
// Edge lists padded to x16 with dummy row n (zero, L1-hot) -> branchless inner
// loop: 1 coalesced es load + shfl broadcast + 8 gathers in flight per slot.
__global__ __launch_bounds__(256) void k_agg(const uint4* __restrict__ hp4,
                                             const int* __restrict__ es,
                                             const int* __restrict__ rowptr,
                                             const int* __restrict__ lenp,
                                             const float* __restrict__ rs,
                                             const float* __restrict__ b,
                                             const float* __restrict__ pert,
                                             float* __restrict__ outp, int n) {
    int lane = threadIdx.x & 63;
    int wv = threadIdx.x >> 6;
    int g = lane >> 4;            // node sub-group 0..3
    int sub = lane & 15;
    int eslot = sub >> 3;         // 0..1
    int q = sub & 7;              // uint4 index within 128B row
    int node = (blockIdx.x * 4 + wv) * 4 + g;
    bool alive = node < n;
    int nc = alive ? node : 0;
    int e0 = rowptr[nc];
    int len = alive ? lenp[nc] : 0;
    float A[8] = {0,0,0,0,0,0,0,0};
    float B[8] = {0,0,0,0,0,0,0,0};
    float C[8] = {0,0,0,0,0,0,0,0};
    float D[8] = {0,0,0,0,0,0,0,0};
    if (alive && eslot == 0) f16acc(hp4[(size_t)nc * 8 + q], A);  // self-loop
    for (int eb = e0; eb < e0 + len; eb += 16) {
        int idx = es[eb + sub];   // 16 coalesced indices for this node
        int i0 = __shfl(idx, 0 + eslot, 16);
        int i1 = __shfl(idx, 2 + eslot, 16);
        int i2 = __shfl(idx, 4 + eslot, 16);
        int i3 = __shfl(idx, 6 + eslot, 16);
        int i4 = __shfl(idx, 8 + eslot, 16);
        int i5 = __shfl(idx, 10 + eslot, 16);
        int i6 = __shfl(idx, 12 + eslot, 16);
        int i7 = __shfl(idx, 14 + eslot, 16);
        uint4 v0 = hp4[(size_t)i0 * 8 + q];
        uint4 v1 = hp4[(size_t)i1 * 8 + q];
        uint4 v2 = hp4[(size_t)i2 * 8 + q];
        uint4 v3 = hp4[(size_t)i3 * 8 + q];
        uint4 v4 = hp4[(size_t)i4 * 8 + q];
        uint4 v5 = hp4[(size_t)i5 * 8 + q];
        uint4 v6 = hp4[(size_t)i6 * 8 + q];
        uint4 v7 = hp4[(size_t)i7 * 8 + q];
        f16acc(v0, A); f16acc(v1, B); f16acc(v2, C); f16acc(v3, D);
        f16acc(v4, A); f16acc(v5, B); f16acc(v6, C); f16acc(v7, D);
    }
#pragma unroll
    for (int j = 0; j < 8; ++j) {
        float v = (A[j] + B[j]) + (C[j] + D[j]);
        v += __shfl_xor(v, 8, 64);  // combine the 2 edge slots
        A[j] = v;
    }
    if (alive && eslot == 0) {
        float r = rs[nc];
        size_t o = (size_t)nc * DD + q * 8;
        float4 p0 = *(const float4*)(pert + o);
        float4 p1 = *(const float4*)(pert + o + 4);
        float4 b0 = *(const float4*)(b + q * 8);
        float4 b1 = *(const float4*)(b + q * 8 + 4);
        float4 r0, r1;
        r0.x = fmaf(r, A[0], b0.x + p0.x);
        r0.y = fmaf(r, A[1], b0.y + p0.y);
        r0.z = fmaf(r, A[2], b0.z + p0.z);
        r0.w = fmaf(r, A[3], b0.w + p0.w);
        r1.x = fmaf(r, A[4], b1.x + p1.x);
        r1.y = fmaf(r, A[5], b1.y + p1.y);
        r1.z = fmaf(r, A[6], b1.z + p1.z);
        r1.w = fmaf(r, A[7], b1.w + p1.w);
        *(float4*)(outp + o) = r0;
        *(float4*)(outp + o + 4) = r1;
    }
}

extern "C" void kernel_launch(void* const* d_in, const int* in_sizes, int n_in,
                              void* d_out, int out_size, void* d_ws, size_t ws_size,
                              hipStream_t stream) {
    const float* x  = (const float*)d_in[0];
    const int*   ei = (const int*)d_in[1];
    const float* W1 = (const float*)d_in[2];
    const float* b1 = (const float*)d_in[3];
    const float* W2 = (const float*)d_in[4];
    const float* b2 = (const float*)d_in[5];
    const float* p1 = (const float*)d_in[6];
    const float* p2 = (const float*)d_in[7];
    float* out = (float*)d_out;

    int n = in_sizes[0] / FIN;
    int E = in_sizes[1] / 2;
    const int* src = ei;
    const int* dst = ei + E;
    int nbuk = (n + BK - 1) / BK;  // 391 for n=100k
    int gb = (n + 63) / 64;

    char* ws = (char*)d_ws;
    size_t off = 0;
    int* gcur   = (int*)(ws + off); off += sizeof(int) * MAXBUK;
    int* rowptr = (int*)(ws + off); off += sizeof(int) * (size_t)n;
    int* lenp   = (int*)(ws + off); off += sizeof(int) * (size_t)n;
    float* rs   = (float*)(ws + off); off += sizeof(float) * (size_t)n;
    int* es     = (int*)(ws + off); off += sizeof(int) * (size_t)nbuk * ESCAP;
    off = (off + 15) & ~(size_t)15;
    unsigned* buf = (unsigned*)(ws + off);
    off += sizeof(unsigned) * (size_t)nbuk * CAP;
    off = (off + 15) & ~(size_t)15;
    _Float16* hpf = (_Float16*)(ws + off);      // f16 [gb*64][64], rows>=n zero
    off += (size_t)gb * 64 * DD * 2;
    off = (off + 15) & ~(size_t)15;
    _Float16* Wt1 = (_Float16*)(ws + off); off += FIN * DD * 2;
    _Float16* Wt2 = (_Float16*)(ws + off); off += DD * DD * 2;
    off = (off + 15) & ~(size_t)15;
    float* agg1 = (float*)(ws + off); off += sizeof(float) * (size_t)n * DD;

    int ab = (n + 15) / 16;        // 4 nodes per wave, 4 waves per block
    int bb = (E + EPB - 1) / EPB;

    hipMemsetAsync(gcur, 0, sizeof(int) * MAXBUK, stream);
    k_prep<<<1, 256, 0, stream>>>(W1, W2, Wt1, Wt2);
    k_bucket<<<bb, 256, 0, stream>>>(src, dst, buf, gcur, E, nbuk);
    k_csr<<<nbuk, 256, 0, stream>>>(buf, gcur, rowptr, lenp, rs, es, n, n);

    k_gemm1<<<gb, 256, 0, stream>>>(x, Wt1, rs, hpf, n);
    k_agg<<<ab, 256, 0, stream>>>((const uint4*)hpf, es, rowptr, lenp, rs, b1, p1, agg1, n);

    k_gemm2<<<gb, 256, 0, stream>>>(agg1, Wt2, rs, hpf, n);
    k_agg<<<ab, 256, 0, stream>>>((const uint4*)hpf, es, rowptr, lenp, rs, b2, p2, out, n);
}

// Round 12
// 167.408 us; speedup vs baseline: 1.2811x; 1.0073x over previous
//
#include <hip/hip_runtime.h>

#define DD 64
#define FIN 128
#define BK 256        // nodes per bucket
#define MAXBUK 512    // supports n <= 131072
#define CAP 8192      // records per bucket region (mean ~4092 at E=1.6M)
#define ESCAP 12288   // padded es slots per bucket
#define EPB 4096      // edges per k_bucket block (16 per thread)

typedef _Float16 half8 __attribute__((ext_vector_type(8)));
typedef _Float16 h2 __attribute__((ext_vector_type(2)));
typedef float f32x4 __attribute__((ext_vector_type(4)));

union U4 { uint4 u; h2 h[4]; };

// pass 1: bucket edges by dst>>8. dst values cached in regs across both passes.
__global__ __launch_bounds__(256) void k_bucket(const int* __restrict__ src,
                                                const int* __restrict__ dst,
                                                unsigned* __restrict__ buf,
                                                int* __restrict__ gcur,
                                                int E, int nbuk) {
    __shared__ int hist[MAXBUK];
    __shared__ int base[MAXBUK];
    int e0 = blockIdx.x * EPB;
    int e1 = min(e0 + EPB, E);
    int dreg[16];
#pragma unroll
    for (int i = 0; i < 16; ++i) {
        int e = e0 + threadIdx.x + i * 256;
        dreg[i] = (e < e1) ? dst[e] : -1;
    }
    for (int i = threadIdx.x; i < nbuk; i += 256) hist[i] = 0;
    __syncthreads();
#pragma unroll
    for (int i = 0; i < 16; ++i)
        if (dreg[i] >= 0) atomicAdd(&hist[dreg[i] >> 8], 1);
    __syncthreads();
    for (int i = threadIdx.x; i < nbuk; i += 256) {
        int c = hist[i];
        base[i] = c ? atomicAdd(&gcur[i], c) : 0;
        hist[i] = 0;  // reuse as local cursor
    }
    __syncthreads();
#pragma unroll
    for (int i = 0; i < 16; ++i) {
        int d = dreg[i];
        if (d >= 0) {
            int e = e0 + threadIdx.x + i * 256;
            int b = d >> 8;
            int off = base[b] + atomicAdd(&hist[b], 1);
            if (off < CAP)
                buf[(size_t)b * CAP + off] = ((unsigned)src[e] << 8) | ((unsigned)d & 255u);
        }
    }
}

// pass 2: one workgroup per bucket. Per-node histogram -> padded (x16) scan ->
// es region at fixed b*ESCAP. Pads point at dummy row (index n, zeroed in gemm).
__global__ __launch_bounds__(256) void k_csr(const unsigned* __restrict__ buf,
                                             const int* __restrict__ gcur,
                                             int* __restrict__ rowptr,
                                             int* __restrict__ lenp,
                                             float* __restrict__ rs,
                                             int* __restrict__ es, int n, int dummy) {
    __shared__ int cnt[BK];
    __shared__ int excl[BK];
    __shared__ int cur[BK];
    __shared__ int wsum[4];
    int b = blockIdx.x;
    int tid = threadIdx.x;
    int lane = tid & 63, wid = tid >> 6;
    cnt[tid] = 0;
    cur[tid] = 0;
    __syncthreads();
    int count = gcur[b];
    const unsigned* rec = buf + (size_t)b * CAP;
    for (int i = tid; i < count; i += 256)
        atomicAdd(&cnt[rec[i] & (BK - 1)], 1);
    __syncthreads();
    int v = cnt[tid];
    int pv = (v + 15) & ~15;  // padded to multiple of 16
    int s = pv;
    for (int off = 1; off < 64; off <<= 1) {
        int t = __shfl_up(s, off, 64);
        if (lane >= off) s += t;
    }
    if (lane == 63) wsum[wid] = s;
    __syncthreads();
    int wo = 0;
    for (int w = 0; w < wid; ++w) wo += wsum[w];
    excl[tid] = s - pv + wo;
    __syncthreads();
    int node = b * BK + tid;
    int base = b * ESCAP;
    if (node < n) {
        rowptr[node] = base + excl[tid];
        lenp[node] = pv;
        rs[node] = rsqrtf((float)(v + 1));  // +1 self-loop
    }
    for (int i = tid; i < count; i += 256) {
        unsigned r = rec[i];
        int local = r & (BK - 1);
        int pos = base + excl[local] + atomicAdd(&cur[local], 1);
        es[pos] = (int)(r >> 8);
    }
    int st = base + excl[tid];
    for (int i = v; i < pv; ++i) es[st + i] = dummy;
}

// transpose + f16-convert weights: Wt1[c][k] = W1[k][c], Wt2[c][k] = W2[k][c]
__global__ __launch_bounds__(256) void k_prep(const float* __restrict__ W1,
                                              const float* __restrict__ W2,
                                              _Float16* __restrict__ Wt1,
                                              _Float16* __restrict__ Wt2) {
    int tid = threadIdx.x;
    for (int i = tid; i < FIN * DD; i += 256) {
        int k = i >> 6, c = i & 63;
        Wt1[c * FIN + k] = (_Float16)W1[i];
    }
    for (int i = tid; i < DD * DD; i += 256) {
        int k = i >> 6, c = i & 63;
        Wt2[c * DD + k] = (_Float16)W2[i];
    }
}

// MFMA f16 GEMM: hpf[row][col] = f16((x[row,:] @ W[:,col]) * rs[row])
// block = 64 rows x 64 cols, 4 waves (wave = 16 rows), K=128. rows >= n zeroed.
__global__ __launch_bounds__(256) void k_gemm1(const float* __restrict__ x,
                                               const _Float16* __restrict__ Wt,
                                               const float* __restrict__ rs,
                                               _Float16* __restrict__ hpf, int n) {
    __shared__ _Float16 sx[64 * 136];
    int row0 = blockIdx.x * 64;
    int tid = threadIdx.x;
    for (int i = tid; i < 2048; i += 256) {  // 64 rows * 32 float4
        int r = i >> 5, c = i & 31;
        int row = row0 + r;
        float4 v = make_float4(0.f, 0.f, 0.f, 0.f);
        if (row < n) v = *(const float4*)(x + (size_t)row * FIN + c * 4);
        union { _Float16 h[4]; uint2 u; } t;
        t.h[0] = (_Float16)v.x; t.h[1] = (_Float16)v.y;
        t.h[2] = (_Float16)v.z; t.h[3] = (_Float16)v.w;
        *(uint2*)(sx + r * 136 + c * 4) = t.u;
    }
    __syncthreads();
    int lane = tid & 63, wave = tid >> 6;
    int r15 = lane & 15, g = lane >> 4;
    half8 a[4];
    const _Float16* ap = sx + (wave * 16 + r15) * 136 + g * 8;
#pragma unroll
    for (int kc = 0; kc < 4; ++kc) a[kc] = *(const half8*)(ap + kc * 32);
    half8 bfr[4][4];
    const _Float16* bp = Wt + (size_t)r15 * FIN + g * 8;
#pragma unroll
    for (int ct = 0; ct < 4; ++ct)
#pragma unroll
        for (int kc = 0; kc < 4; ++kc)
            bfr[ct][kc] = *(const half8*)(bp + ct * 16 * FIN + kc * 32);
    f32x4 acc[4] = {{0.f,0.f,0.f,0.f},{0.f,0.f,0.f,0.f},{0.f,0.f,0.f,0.f},{0.f,0.f,0.f,0.f}};
#pragma unroll
    for (int ct = 0; ct < 4; ++ct)
#pragma unroll
        for (int kc = 0; kc < 4; ++kc)
            acc[ct] = __builtin_amdgcn_mfma_f32_16x16x32_f16(a[kc], bfr[ct][kc], acc[ct], 0, 0, 0);
    __syncthreads();
#pragma unroll
    for (int reg = 0; reg < 4; ++reg) {
        int rowl = wave * 16 + g * 4 + reg;
        int row = row0 + rowl;
        float sc = (row < n) ? rs[row] : 0.f;
#pragma unroll
        for (int ct = 0; ct < 4; ++ct)
            sx[rowl * 72 + ct * 16 + r15] = (_Float16)(acc[ct][reg] * sc);
    }
    __syncthreads();
    for (int i = tid; i < 1024; i += 256) {  // 64 rows * 16 uint2
        int r = i >> 4, q = i & 15;
        uint2 v = *(const uint2*)(sx + r * 72 + q * 4);
        *(uint2*)(hpf + (size_t)(row0 + r) * DD + q * 4) = v;
    }
}

// MFMA f16 GEMM, f16 relu'd input: hpf[row][col] = f16((ain[row,:] @ W[:,col]) * rs[row])
__global__ __launch_bounds__(256) void k_gemm2(const _Float16* __restrict__ ain,
                                               const _Float16* __restrict__ Wt,
                                               const float* __restrict__ rs,
                                               _Float16* __restrict__ hpf, int n) {
    __shared__ _Float16 sx[64 * 72];
    int row0 = blockIdx.x * 64;
    int tid = threadIdx.x;
    for (int i = tid; i < 512; i += 256) {  // 64 rows * 8 x 16B
        int r = i >> 3, c = i & 7;
        int row = row0 + r;
        uint4 v = make_uint4(0u, 0u, 0u, 0u);
        if (row < n) v = *(const uint4*)(ain + (size_t)row * DD + c * 8);
        *(uint4*)(sx + r * 72 + c * 8) = v;
    }
    __syncthreads();
    int lane = tid & 63, wave = tid >> 6;
    int r15 = lane & 15, g = lane >> 4;
    half8 a[2];
    const _Float16* ap = sx + (wave * 16 + r15) * 72 + g * 8;
#pragma unroll
    for (int kc = 0; kc < 2; ++kc) a[kc] = *(const half8*)(ap + kc * 32);
    half8 bfr[4][2];
    const _Float16* bp = Wt + (size_t)r15 * DD + g * 8;
#pragma unroll
    for (int ct = 0; ct < 4; ++ct)
#pragma unroll
        for (int kc = 0; kc < 2; ++kc)
            bfr[ct][kc] = *(const half8*)(bp + ct * 16 * DD + kc * 32);
    f32x4 acc[4] = {{0.f,0.f,0.f,0.f},{0.f,0.f,0.f,0.f},{0.f,0.f,0.f,0.f},{0.f,0.f,0.f,0.f}};
#pragma unroll
    for (int ct = 0; ct < 4; ++ct)
#pragma unroll
        for (int kc = 0; kc < 2; ++kc)
            acc[ct] = __builtin_amdgcn_mfma_f32_16x16x32_f16(a[kc], bfr[ct][kc], acc[ct], 0, 0, 0);
    __syncthreads();
#pragma unroll
    for (int reg = 0; reg < 4; ++reg) {
        int rowl = wave * 16 + g * 4 + reg;
        int row = row0 + rowl;
        float sc = (row < n) ? rs[row] : 0.f;
#pragma unroll
        for (int ct = 0; ct < 4; ++ct)
            sx[rowl * 72 + ct * 16 + r15] = (_Float16)(acc[ct][reg] * sc);
    }
    __syncthreads();
    for (int i = tid; i < 1024; i += 256) {
        int r = i >> 4, q = i & 15;
        uint2 v = *(const uint2*)(sx + r * 72 + q * 4);
        *(uint2*)(hpf + (size_t)(row0 + r) * DD + q * 4) = v;
    }
}

// gather aggregation: 4 nodes/wave, 16 lanes/node (2 edge-slots x 8 lanes).
// Packed f16x2 accumulation (v_pk_add_f16), f32 combine in epilogue.
// F16OUT: write relu(result) as f16 (layer 1). else f32 (layer 2 -> d_out).
template <bool F16OUT>
__global__ __launch_bounds__(256) void k_agg(const uint4* __restrict__ hp4,
                                             const int* __restrict__ es,
                                             const int* __restrict__ rowptr,
                                             const int* __restrict__ lenp,
                                             const float* __restrict__ rs,
                                             const float* __restrict__ b,
                                             const float* __restrict__ pert,
                                             float* __restrict__ outp,
                                             _Float16* __restrict__ outh, int n) {
    int lane = threadIdx.x & 63;
    int wv = threadIdx.x >> 6;
    int g = lane >> 4;            // node sub-group 0..3
    int sub = lane & 15;
    int eslot = sub >> 3;         // 0..1
    int q = sub & 7;              // uint4 index within 128B row
    int node = (blockIdx.x * 4 + wv) * 4 + g;
    bool alive = node < n;
    int nc = alive ? node : 0;
    int e0 = rowptr[nc];
    int len = alive ? lenp[nc] : 0;
    h2 A[4] = {{0,0},{0,0},{0,0},{0,0}};
    h2 B[4] = {{0,0},{0,0},{0,0},{0,0}};
    h2 C[4] = {{0,0},{0,0},{0,0},{0,0}};
    h2 D[4] = {{0,0},{0,0},{0,0},{0,0}};
    if (alive && eslot == 0) {    // self-loop
        U4 t; t.u = hp4[(size_t)nc * 8 + q];
        A[0] += t.h[0]; A[1] += t.h[1]; A[2] += t.h[2]; A[3] += t.h[3];
    }
    for (int eb = e0; eb < e0 + len; eb += 16) {
        int idx = es[eb + sub];   // 16 coalesced indices for this node
        int i0 = __shfl(idx, 0 + eslot, 16);
        int i1 = __shfl(idx, 2 + eslot, 16);
        int i2 = __shfl(idx, 4 + eslot, 16);
        int i3 = __shfl(idx, 6 + eslot, 16);
        int i4 = __shfl(idx, 8 + eslot, 16);
        int i5 = __shfl(idx, 10 + eslot, 16);
        int i6 = __shfl(idx, 12 + eslot, 16);
        int i7 = __shfl(idx, 14 + eslot, 16);
        U4 v0, v1, v2, v3, v4, v5, v6, v7;
        v0.u = hp4[(size_t)i0 * 8 + q];
        v1.u = hp4[(size_t)i1 * 8 + q];
        v2.u = hp4[(size_t)i2 * 8 + q];
        v3.u = hp4[(size_t)i3 * 8 + q];
        v4.u = hp4[(size_t)i4 * 8 + q];
        v5.u = hp4[(size_t)i5 * 8 + q];
        v6.u = hp4[(size_t)i6 * 8 + q];
        v7.u = hp4[(size_t)i7 * 8 + q];
#pragma unroll
        for (int k = 0; k < 4; ++k) {
            A[k] += v0.h[k]; B[k] += v1.h[k]; C[k] += v2.h[k]; D[k] += v3.h[k];
            A[k] += v4.h[k]; B[k] += v5.h[k]; C[k] += v6.h[k]; D[k] += v7.h[k];
        }
    }
    float F[8];
#pragma unroll
    for (int k = 0; k < 4; ++k) {
        F[2 * k]     = ((float)A[k].x + (float)B[k].x) + ((float)C[k].x + (float)D[k].x);
        F[2 * k + 1] = ((float)A[k].y + (float)B[k].y) + ((float)C[k].y + (float)D[k].y);
    }
#pragma unroll
    for (int j = 0; j < 8; ++j)
        F[j] += __shfl_xor(F[j], 8, 64);  // combine the 2 edge slots
    if (alive && eslot == 0) {
        float r = rs[nc];
        size_t o = (size_t)nc * DD + q * 8;
        float4 p0 = *(const float4*)(pert + o);
        float4 p1 = *(const float4*)(pert + o + 4);
        float4 b0 = *(const float4*)(b + q * 8);
        float4 b1 = *(const float4*)(b + q * 8 + 4);
        float r0 = fmaf(r, F[0], b0.x + p0.x);
        float r1 = fmaf(r, F[1], b0.y + p0.y);
        float r2 = fmaf(r, F[2], b0.z + p0.z);
        float r3 = fmaf(r, F[3], b0.w + p0.w);
        float r4 = fmaf(r, F[4], b1.x + p1.x);
        float r5 = fmaf(r, F[5], b1.y + p1.y);
        float r6 = fmaf(r, F[6], b1.z + p1.z);
        float r7 = fmaf(r, F[7], b1.w + p1.w);
        if (F16OUT) {
            union { _Float16 h[8]; uint4 u; } t;
            t.h[0] = (_Float16)fmaxf(r0, 0.f);
            t.h[1] = (_Float16)fmaxf(r1, 0.f);
            t.h[2] = (_Float16)fmaxf(r2, 0.f);
            t.h[3] = (_Float16)fmaxf(r3, 0.f);
            t.h[4] = (_Float16)fmaxf(r4, 0.f);
            t.h[5] = (_Float16)fmaxf(r5, 0.f);
            t.h[6] = (_Float16)fmaxf(r6, 0.f);
            t.h[7] = (_Float16)fmaxf(r7, 0.f);
            *(uint4*)(outh + o) = t.u;
        } else {
            *(float4*)(outp + o) = make_float4(r0, r1, r2, r3);
            *(float4*)(outp + o + 4) = make_float4(r4, r5, r6, r7);
        }
    }
}

extern "C" void kernel_launch(void* const* d_in, const int* in_sizes, int n_in,
                              void* d_out, int out_size, void* d_ws, size_t ws_size,
                              hipStream_t stream) {
    const float* x  = (const float*)d_in[0];
    const int*   ei = (const int*)d_in[1];
    const float* W1 = (const float*)d_in[2];
    const float* b1 = (const float*)d_in[3];
    const float* W2 = (const float*)d_in[4];
    const float* b2 = (const float*)d_in[5];
    const float* p1 = (const float*)d_in[6];
    const float* p2 = (const float*)d_in[7];
    float* out = (float*)d_out;

    int n = in_sizes[0] / FIN;
    int E = in_sizes[1] / 2;
    const int* src = ei;
    const int* dst = ei + E;
    int nbuk = (n + BK - 1) / BK;  // 391 for n=100k
    int gb = (n + 63) / 64;

    char* ws = (char*)d_ws;
    size_t off = 0;
    int* gcur   = (int*)(ws + off); off += sizeof(int) * MAXBUK;
    int* rowptr = (int*)(ws + off); off += sizeof(int) * (size_t)n;
    int* lenp   = (int*)(ws + off); off += sizeof(int) * (size_t)n;
    float* rs   = (float*)(ws + off); off += sizeof(float) * (size_t)n;
    int* es     = (int*)(ws + off); off += sizeof(int) * (size_t)nbuk * ESCAP;
    off = (off + 15) & ~(size_t)15;
    unsigned* buf = (unsigned*)(ws + off);
    off += sizeof(unsigned) * (size_t)nbuk * CAP;
    off = (off + 15) & ~(size_t)15;
    _Float16* hpf = (_Float16*)(ws + off);      // f16 [gb*64][64], rows>=n zero
    off += (size_t)gb * 64 * DD * 2;
    off = (off + 15) & ~(size_t)15;
    _Float16* hpf2 = (_Float16*)(ws + off);     // f16 relu'd agg1
    off += (size_t)gb * 64 * DD * 2;
    off = (off + 15) & ~(size_t)15;
    _Float16* Wt1 = (_Float16*)(ws + off); off += FIN * DD * 2;
    _Float16* Wt2 = (_Float16*)(ws + off); off += DD * DD * 2;

    int ab = (n + 15) / 16;        // 4 nodes per wave, 4 waves per block
    int bb = (E + EPB - 1) / EPB;

    hipMemsetAsync(gcur, 0, sizeof(int) * MAXBUK, stream);
    k_prep<<<1, 256, 0, stream>>>(W1, W2, Wt1, Wt2);
    k_bucket<<<bb, 256, 0, stream>>>(src, dst, buf, gcur, E, nbuk);
    k_csr<<<nbuk, 256, 0, stream>>>(buf, gcur, rowptr, lenp, rs, es, n, n);

    k_gemm1<<<gb, 256, 0, stream>>>(x, Wt1, rs, hpf, n);
    k_agg<true><<<ab, 256, 0, stream>>>((const uint4*)hpf, es, rowptr, lenp, rs,
                                        b1, p1, nullptr, hpf2, n);
    k_gemm2<<<gb, 256, 0, stream>>>(hpf2, Wt2, rs, hpf, n);
    k_agg<false><<<ab, 256, 0, stream>>>((const uint4*)hpf, es, rowptr, lenp, rs,
                                         b2, p2, out, nullptr, n);
}

// Round 13
// 163.302 us; speedup vs baseline: 1.3133x; 1.0251x over previous
//
#include <hip/hip_runtime.h>

#define DD 64
#define FIN 128
#define BK 256        // nodes per bucket
#define MAXBUK 512    // supports n <= 131072
#define CAP 8192      // records per bucket region (mean ~4092 at E=1.6M)
#define ESCAP 12288   // padded es slots per bucket
#define EPB 4096      // edges per k_bucket block (16 per thread)

typedef _Float16 half8 __attribute__((ext_vector_type(8)));
typedef _Float16 h2 __attribute__((ext_vector_type(2)));
typedef float f32x4 __attribute__((ext_vector_type(4)));

union U4 { uint4 u; h2 h[4]; };

// pass 1: bucket edges by dst>>8. dst values cached in regs across both passes.
__global__ __launch_bounds__(256) void k_bucket(const int* __restrict__ src,
                                                const int* __restrict__ dst,
                                                unsigned* __restrict__ buf,
                                                int* __restrict__ gcur,
                                                int E, int nbuk) {
    __shared__ int hist[MAXBUK];
    __shared__ int base[MAXBUK];
    int e0 = blockIdx.x * EPB;
    int e1 = min(e0 + EPB, E);
    int dreg[16];
#pragma unroll
    for (int i = 0; i < 16; ++i) {
        int e = e0 + threadIdx.x + i * 256;
        dreg[i] = (e < e1) ? dst[e] : -1;
    }
    for (int i = threadIdx.x; i < nbuk; i += 256) hist[i] = 0;
    __syncthreads();
#pragma unroll
    for (int i = 0; i < 16; ++i)
        if (dreg[i] >= 0) atomicAdd(&hist[dreg[i] >> 8], 1);
    __syncthreads();
    for (int i = threadIdx.x; i < nbuk; i += 256) {
        int c = hist[i];
        base[i] = c ? atomicAdd(&gcur[i], c) : 0;
        hist[i] = 0;  // reuse as local cursor
    }
    __syncthreads();
#pragma unroll
    for (int i = 0; i < 16; ++i) {
        int d = dreg[i];
        if (d >= 0) {
            int e = e0 + threadIdx.x + i * 256;
            int b = d >> 8;
            int off = base[b] + atomicAdd(&hist[b], 1);
            if (off < CAP)
                buf[(size_t)b * CAP + off] = ((unsigned)src[e] << 8) | ((unsigned)d & 255u);
        }
    }
}

// pass 2: one workgroup per bucket. Per-node histogram -> padded (x16) scan ->
// es region at fixed b*ESCAP. Pads point at dummy row (index n, zeroed in gemm).
__global__ __launch_bounds__(256) void k_csr(const unsigned* __restrict__ buf,
                                             const int* __restrict__ gcur,
                                             int* __restrict__ rowptr,
                                             int* __restrict__ lenp,
                                             float* __restrict__ rs,
                                             int* __restrict__ es, int n, int dummy) {
    __shared__ int cnt[BK];
    __shared__ int excl[BK];
    __shared__ int cur[BK];
    __shared__ int wsum[4];
    int b = blockIdx.x;
    int tid = threadIdx.x;
    int lane = tid & 63, wid = tid >> 6;
    cnt[tid] = 0;
    cur[tid] = 0;
    __syncthreads();
    int count = gcur[b];
    const unsigned* rec = buf + (size_t)b * CAP;
    for (int i = tid; i < count; i += 256)
        atomicAdd(&cnt[rec[i] & (BK - 1)], 1);
    __syncthreads();
    int v = cnt[tid];
    int pv = (v + 15) & ~15;  // padded to multiple of 16
    int s = pv;
    for (int off = 1; off < 64; off <<= 1) {
        int t = __shfl_up(s, off, 64);
        if (lane >= off) s += t;
    }
    if (lane == 63) wsum[wid] = s;
    __syncthreads();
    int wo = 0;
    for (int w = 0; w < wid; ++w) wo += wsum[w];
    excl[tid] = s - pv + wo;
    __syncthreads();
    int node = b * BK + tid;
    int base = b * ESCAP;
    if (node < n) {
        rowptr[node] = base + excl[tid];
        lenp[node] = pv;
        rs[node] = rsqrtf((float)(v + 1));  // +1 self-loop
    }
    for (int i = tid; i < count; i += 256) {
        unsigned r = rec[i];
        int local = r & (BK - 1);
        int pos = base + excl[local] + atomicAdd(&cur[local], 1);
        es[pos] = (int)(r >> 8);
    }
    int st = base + excl[tid];
    for (int i = v; i < pv; ++i) es[st + i] = dummy;
}

// transpose + f16-convert weights; also zeroes gcur (replaces hipMemsetAsync,
// whose fillBuffer dispatch showed ~40us in rocprof).
__global__ __launch_bounds__(256) void k_prep(const float* __restrict__ W1,
                                              const float* __restrict__ W2,
                                              _Float16* __restrict__ Wt1,
                                              _Float16* __restrict__ Wt2,
                                              int* __restrict__ gcur) {
    int tid = threadIdx.x;
    gcur[tid] = 0;
    gcur[tid + 256] = 0;
    for (int i = tid; i < FIN * DD; i += 256) {
        int k = i >> 6, c = i & 63;
        Wt1[c * FIN + k] = (_Float16)W1[i];
    }
    for (int i = tid; i < DD * DD; i += 256) {
        int k = i >> 6, c = i & 63;
        Wt2[c * DD + k] = (_Float16)W2[i];
    }
}

// MFMA f16 GEMM: hpf[row][col] = f16((x[row,:] @ W[:,col]) * rs[row])
// block = 64 rows x 64 cols, 4 waves (wave = 16 rows), K=128. rows >= n zeroed.
__global__ __launch_bounds__(256) void k_gemm1(const float* __restrict__ x,
                                               const _Float16* __restrict__ Wt,
                                               const float* __restrict__ rs,
                                               _Float16* __restrict__ hpf, int n) {
    __shared__ _Float16 sx[64 * 136];
    int row0 = blockIdx.x * 64;
    int tid = threadIdx.x;
    for (int i = tid; i < 2048; i += 256) {  // 64 rows * 32 float4
        int r = i >> 5, c = i & 31;
        int row = row0 + r;
        float4 v = make_float4(0.f, 0.f, 0.f, 0.f);
        if (row < n) v = *(const float4*)(x + (size_t)row * FIN + c * 4);
        union { _Float16 h[4]; uint2 u; } t;
        t.h[0] = (_Float16)v.x; t.h[1] = (_Float16)v.y;
        t.h[2] = (_Float16)v.z; t.h[3] = (_Float16)v.w;
        *(uint2*)(sx + r * 136 + c * 4) = t.u;
    }
    __syncthreads();
    int lane = tid & 63, wave = tid >> 6;
    int r15 = lane & 15, g = lane >> 4;
    half8 a[4];
    const _Float16* ap = sx + (wave * 16 + r15) * 136 + g * 8;
#pragma unroll
    for (int kc = 0; kc < 4; ++kc) a[kc] = *(const half8*)(ap + kc * 32);
    half8 bfr[4][4];
    const _Float16* bp = Wt + (size_t)r15 * FIN + g * 8;
#pragma unroll
    for (int ct = 0; ct < 4; ++ct)
#pragma unroll
        for (int kc = 0; kc < 4; ++kc)
            bfr[ct][kc] = *(const half8*)(bp + ct * 16 * FIN + kc * 32);
    f32x4 acc[4] = {{0.f,0.f,0.f,0.f},{0.f,0.f,0.f,0.f},{0.f,0.f,0.f,0.f},{0.f,0.f,0.f,0.f}};
#pragma unroll
    for (int ct = 0; ct < 4; ++ct)
#pragma unroll
        for (int kc = 0; kc < 4; ++kc)
            acc[ct] = __builtin_amdgcn_mfma_f32_16x16x32_f16(a[kc], bfr[ct][kc], acc[ct], 0, 0, 0);
    __syncthreads();
#pragma unroll
    for (int reg = 0; reg < 4; ++reg) {
        int rowl = wave * 16 + g * 4 + reg;
        int row = row0 + rowl;
        float sc = (row < n) ? rs[row] : 0.f;
#pragma unroll
        for (int ct = 0; ct < 4; ++ct)
            sx[rowl * 72 + ct * 16 + r15] = (_Float16)(acc[ct][reg] * sc);
    }
    __syncthreads();
    for (int i = tid; i < 1024; i += 256) {  // 64 rows * 16 uint2
        int r = i >> 4, q = i & 15;
        uint2 v = *(const uint2*)(sx + r * 72 + q * 4);
        *(uint2*)(hpf + (size_t)(row0 + r) * DD + q * 4) = v;
    }
}

// MFMA f16 GEMM, f16 relu'd input: hpf[row][col] = f16((ain[row,:] @ W[:,col]) * rs[row])
__global__ __launch_bounds__(256) void k_gemm2(const _Float16* __restrict__ ain,
                                               const _Float16* __restrict__ Wt,
                                               const float* __restrict__ rs,
                                               _Float16* __restrict__ hpf, int n) {
    __shared__ _Float16 sx[64 * 72];
    int row0 = blockIdx.x * 64;
    int tid = threadIdx.x;
    for (int i = tid; i < 512; i += 256) {  // 64 rows * 8 x 16B
        int r = i >> 3, c = i & 7;
        int row = row0 + r;
        uint4 v = make_uint4(0u, 0u, 0u, 0u);
        if (row < n) v = *(const uint4*)(ain + (size_t)row * DD + c * 8);
        *(uint4*)(sx + r * 72 + c * 8) = v;
    }
    __syncthreads();
    int lane = tid & 63, wave = tid >> 6;
    int r15 = lane & 15, g = lane >> 4;
    half8 a[2];
    const _Float16* ap = sx + (wave * 16 + r15) * 72 + g * 8;
#pragma unroll
    for (int kc = 0; kc < 2; ++kc) a[kc] = *(const half8*)(ap + kc * 32);
    half8 bfr[4][2];
    const _Float16* bp = Wt + (size_t)r15 * DD + g * 8;
#pragma unroll
    for (int ct = 0; ct < 4; ++ct)
#pragma unroll
        for (int kc = 0; kc < 2; ++kc)
            bfr[ct][kc] = *(const half8*)(bp + ct * 16 * DD + kc * 32);
    f32x4 acc[4] = {{0.f,0.f,0.f,0.f},{0.f,0.f,0.f,0.f},{0.f,0.f,0.f,0.f},{0.f,0.f,0.f,0.f}};
#pragma unroll
    for (int ct = 0; ct < 4; ++ct)
#pragma unroll
        for (int kc = 0; kc < 2; ++kc)
            acc[ct] = __builtin_amdgcn_mfma_f32_16x16x32_f16(a[kc], bfr[ct][kc], acc[ct], 0, 0, 0);
    __syncthreads();
#pragma unroll
    for (int reg = 0; reg < 4; ++reg) {
        int rowl = wave * 16 + g * 4 + reg;
        int row = row0 + rowl;
        float sc = (row < n) ? rs[row] : 0.f;
#pragma unroll
        for (int ct = 0; ct < 4; ++ct)
            sx[rowl * 72 + ct * 16 + r15] = (_Float16)(acc[ct][reg] * sc);
    }
    __syncthreads();
    for (int i = tid; i < 1024; i += 256) {
        int r = i >> 4, q = i & 15;
        uint2 v = *(const uint2*)(sx + r * 72 + q * 4);
        *(uint2*)(hpf + (size_t)(row0 + r) * DD + q * 4) = v;
    }
}

// gather aggregation: 4 nodes/wave, 16 lanes/node (2 edge-slots x 8 lanes).
// Packed f16x2 accumulation; es batch prefetch breaks the load->shfl->gather
// dependency chain for multi-batch nodes.
template <bool F16OUT>
__global__ __launch_bounds__(256) void k_agg(const uint4* __restrict__ hp4,
                                             const int* __restrict__ es,
                                             const int* __restrict__ rowptr,
                                             const int* __restrict__ lenp,
                                             const float* __restrict__ rs,
                                             const float* __restrict__ b,
                                             const float* __restrict__ pert,
                                             float* __restrict__ outp,
                                             _Float16* __restrict__ outh, int n) {
    int lane = threadIdx.x & 63;
    int wv = threadIdx.x >> 6;
    int g = lane >> 4;            // node sub-group 0..3
    int sub = lane & 15;
    int eslot = sub >> 3;         // 0..1
    int q = sub & 7;              // uint4 index within 128B row
    int node = (blockIdx.x * 4 + wv) * 4 + g;
    bool alive = node < n;
    int nc = alive ? node : 0;
    int e0 = rowptr[nc];
    int len = alive ? lenp[nc] : 0;
    int nbt = len >> 4;           // 16-edge batches
    h2 A[4] = {{0,0},{0,0},{0,0},{0,0}};
    h2 B[4] = {{0,0},{0,0},{0,0},{0,0}};
    h2 C[4] = {{0,0},{0,0},{0,0},{0,0}};
    h2 D[4] = {{0,0},{0,0},{0,0},{0,0}};
    if (alive && eslot == 0) {    // self-loop
        U4 t; t.u = hp4[(size_t)nc * 8 + q];
        A[0] += t.h[0]; A[1] += t.h[1]; A[2] += t.h[2]; A[3] += t.h[3];
    }
    int idx = nbt ? es[e0 + sub] : 0;
    for (int t = 0; t < nbt; ++t) {
        int pa = (t + 1 < nbt) ? (e0 + (t + 1) * 16 + sub) : (e0 + sub);
        int idxn = nbt ? es[pa] : 0;  // prefetch next batch (or harmless reload)
        int i0 = __shfl(idx, 0 + eslot, 16);
        int i1 = __shfl(idx, 2 + eslot, 16);
        int i2 = __shfl(idx, 4 + eslot, 16);
        int i3 = __shfl(idx, 6 + eslot, 16);
        int i4 = __shfl(idx, 8 + eslot, 16);
        int i5 = __shfl(idx, 10 + eslot, 16);
        int i6 = __shfl(idx, 12 + eslot, 16);
        int i7 = __shfl(idx, 14 + eslot, 16);
        U4 v0, v1, v2, v3, v4, v5, v6, v7;
        v0.u = hp4[(size_t)i0 * 8 + q];
        v1.u = hp4[(size_t)i1 * 8 + q];
        v2.u = hp4[(size_t)i2 * 8 + q];
        v3.u = hp4[(size_t)i3 * 8 + q];
        v4.u = hp4[(size_t)i4 * 8 + q];
        v5.u = hp4[(size_t)i5 * 8 + q];
        v6.u = hp4[(size_t)i6 * 8 + q];
        v7.u = hp4[(size_t)i7 * 8 + q];
#pragma unroll
        for (int k = 0; k < 4; ++k) {
            A[k] += v0.h[k]; B[k] += v1.h[k]; C[k] += v2.h[k]; D[k] += v3.h[k];
            A[k] += v4.h[k]; B[k] += v5.h[k]; C[k] += v6.h[k]; D[k] += v7.h[k];
        }
        idx = idxn;
    }
    float F[8];
#pragma unroll
    for (int k = 0; k < 4; ++k) {
        F[2 * k]     = ((float)A[k].x + (float)B[k].x) + ((float)C[k].x + (float)D[k].x);
        F[2 * k + 1] = ((float)A[k].y + (float)B[k].y) + ((float)C[k].y + (float)D[k].y);
    }
#pragma unroll
    for (int j = 0; j < 8; ++j)
        F[j] += __shfl_xor(F[j], 8, 64);  // combine the 2 edge slots
    if (alive && eslot == 0) {
        float r = rs[nc];
        size_t o = (size_t)nc * DD + q * 8;
        float4 p0 = *(const float4*)(pert + o);
        float4 p1 = *(const float4*)(pert + o + 4);
        float4 b0 = *(const float4*)(b + q * 8);
        float4 b1 = *(const float4*)(b + q * 8 + 4);
        float r0 = fmaf(r, F[0], b0.x + p0.x);
        float r1 = fmaf(r, F[1], b0.y + p0.y);
        float r2 = fmaf(r, F[2], b0.z + p0.z);
        float r3 = fmaf(r, F[3], b0.w + p0.w);
        float r4 = fmaf(r, F[4], b1.x + p1.x);
        float r5 = fmaf(r, F[5], b1.y + p1.y);
        float r6 = fmaf(r, F[6], b1.z + p1.z);
        float r7 = fmaf(r, F[7], b1.w + p1.w);
        if (F16OUT) {
            union { _Float16 h[8]; uint4 u; } t;
            t.h[0] = (_Float16)fmaxf(r0, 0.f);
            t.h[1] = (_Float16)fmaxf(r1, 0.f);
            t.h[2] = (_Float16)fmaxf(r2, 0.f);
            t.h[3] = (_Float16)fmaxf(r3, 0.f);
            t.h[4] = (_Float16)fmaxf(r4, 0.f);
            t.h[5] = (_Float16)fmaxf(r5, 0.f);
            t.h[6] = (_Float16)fmaxf(r6, 0.f);
            t.h[7] = (_Float16)fmaxf(r7, 0.f);
            *(uint4*)(outh + o) = t.u;
        } else {
            *(float4*)(outp + o) = make_float4(r0, r1, r2, r3);
            *(float4*)(outp + o + 4) = make_float4(r4, r5, r6, r7);
        }
    }
}

extern "C" void kernel_launch(void* const* d_in, const int* in_sizes, int n_in,
                              void* d_out, int out_size, void* d_ws, size_t ws_size,
                              hipStream_t stream) {
    const float* x  = (const float*)d_in[0];
    const int*   ei = (const int*)d_in[1];
    const float* W1 = (const float*)d_in[2];
    const float* b1 = (const float*)d_in[3];
    const float* W2 = (const float*)d_in[4];
    const float* b2 = (const float*)d_in[5];
    const float* p1 = (const float*)d_in[6];
    const float* p2 = (const float*)d_in[7];
    float* out = (float*)d_out;

    int n = in_sizes[0] / FIN;
    int E = in_sizes[1] / 2;
    const int* src = ei;
    const int* dst = ei + E;
    int nbuk = (n + BK - 1) / BK;  // 391 for n=100k
    int gb = (n + 63) / 64;

    char* ws = (char*)d_ws;
    size_t off = 0;
    int* gcur   = (int*)(ws + off); off += sizeof(int) * MAXBUK;
    int* rowptr = (int*)(ws + off); off += sizeof(int) * (size_t)n;
    int* lenp   = (int*)(ws + off); off += sizeof(int) * (size_t)n;
    float* rs   = (float*)(ws + off); off += sizeof(float) * (size_t)n;
    int* es     = (int*)(ws + off); off += sizeof(int) * (size_t)nbuk * ESCAP;
    off = (off + 15) & ~(size_t)15;
    unsigned* buf = (unsigned*)(ws + off);
    off += sizeof(unsigned) * (size_t)nbuk * CAP;
    off = (off + 15) & ~(size_t)15;
    _Float16* hpf = (_Float16*)(ws + off);      // f16 [gb*64][64], rows>=n zero
    off += (size_t)gb * 64 * DD * 2;
    off = (off + 15) & ~(size_t)15;
    _Float16* hpf2 = (_Float16*)(ws + off);     // f16 relu'd agg1
    off += (size_t)gb * 64 * DD * 2;
    off = (off + 15) & ~(size_t)15;
    _Float16* Wt1 = (_Float16*)(ws + off); off += FIN * DD * 2;
    _Float16* Wt2 = (_Float16*)(ws + off); off += DD * DD * 2;

    int ab = (n + 15) / 16;        // 4 nodes per wave, 4 waves per block
    int bb = (E + EPB - 1) / EPB;

    k_prep<<<1, 256, 0, stream>>>(W1, W2, Wt1, Wt2, gcur);
    k_bucket<<<bb, 256, 0, stream>>>(src, dst, buf, gcur, E, nbuk);
    k_csr<<<nbuk, 256, 0, stream>>>(buf, gcur, rowptr, lenp, rs, es, n, n);

    k_gemm1<<<gb, 256, 0, stream>>>(x, Wt1, rs, hpf, n);
    k_agg<true><<<ab, 256, 0, stream>>>((const uint4*)hpf, es, rowptr, lenp, rs,
                                        b1, p1, nullptr, hpf2, n);
    k_gemm2<<<gb, 256, 0, stream>>>(hpf2, Wt2, rs, hpf, n);
    k_agg<false><<<ab, 256, 0, stream>>>((const uint4*)hpf, es, rowptr, lenp, rs,
                                         b2, p2, out, nullptr, n);
}